// Round 11
// baseline (189.167 us; speedup 1.0000x reference)
//
#include <hip/hip_runtime.h>
#include <hip/hip_fp16.h>

// GCN 2-layer: x[N,128] -> GCNConv(W1[128,64]) -> relu -> GCNConv(W2[64,32])
// out[d] = dis[d] * (g[d] + sum_{e: dst=d} g[src]) + b,  g = (x@W)*dis.
// R10: DAG reduction. (1) hist+scan+scan+scatter -> ONE kernel w/ fixed-cap
//      buckets (CAP=8192/bucket, atomic chunk reservation, <=50k atomics).
//      (2) gemm2 fused into gather1 epilogue (wave holds full h[d] row;
//      per-wave LDS stage, W2 in LDS; h never touches HBM).
//      6 dispatches (was 9).

#define F_IN 128
#define F_MID 64
#define F_OUT 32
#define NBLK 256
#define CAP 8192   // max edges/bucket: mean 4096, 6-sigma ~4500 -> safe

#define RFL(x) __builtin_amdgcn_readfirstlane(x)

__device__ __forceinline__ void h8acc(float* a, const uint4& v) {
    const __half2* hp = (const __half2*)&v;
#pragma unroll
    for (int i = 0; i < 4; ++i) {
        float2 f = __half22float2(hp[i]);
        a[2 * i]     += f.x;
        a[2 * i + 1] += f.y;
    }
}

__device__ __forceinline__ uint4 pack8(const float4& a, const float4& b) {
    union { uint4 u; __half2 h[4]; } pk;
    pk.h[0] = __float22half2_rn(make_float2(a.x, a.y));
    pk.h[1] = __float22half2_rn(make_float2(a.z, a.w));
    pk.h[2] = __float22half2_rn(make_float2(b.x, b.y));
    pk.h[3] = __float22half2_rn(make_float2(b.z, b.w));
    return pk.u;
}

// ---- Build pass 1: LDS histogram + atomic chunk reservation + scatter ----
__global__ __launch_bounds__(256) void k_build_scatter(
    const int* __restrict__ src, const int* __restrict__ dst, int E, int chunk,
    int nbuk, int* __restrict__ cursor, int* __restrict__ esort) {
    __shared__ int cnt[256];
    __shared__ int off[256];
    int t = threadIdx.x;
    cnt[t] = 0;
    __syncthreads();
    int e0 = blockIdx.x * chunk;
    int e1 = min(E, e0 + chunk);
    for (int e = e0 + t; e < e1; e += 256)
        atomicAdd(&cnt[dst[e] >> 8], 1);
    __syncthreads();
    if (t < nbuk) {
        int c = cnt[t];
        off[t] = t * CAP + (c ? atomicAdd(&cursor[t], c) : 0);
    }
    __syncthreads();
    for (int e = e0 + t; e < e1; e += 256) {
        int d = dst[e];
        int pos = atomicAdd(&off[d >> 8], 1);
        esort[pos] = (src[e] << 8) | (d & 255);   // src < 2^23
    }
}

// ---- Build pass 2: per-bucket exact CSR: deg, rowstart, dis, ordered col ----
__global__ __launch_bounds__(256) void k_bucket_csr(
    const int* __restrict__ esort, const int* __restrict__ cursor, int n,
    int* __restrict__ rowstart, int* __restrict__ deg, float* __restrict__ dis,
    int* __restrict__ col) {
    __shared__ int cnt[256];
    __shared__ int s[256];
    __shared__ int cur[256];
    int b = blockIdx.x;
    int t = threadIdx.x;
    int node0 = b << 8;
    int e0 = b * CAP;
    int e1 = e0 + cursor[b];
    cnt[t] = 0;
    __syncthreads();
    for (int e = e0 + t; e < e1; e += 256)
        atomicAdd(&cnt[esort[e] & 255], 1);
    __syncthreads();
    int v = cnt[t];
    s[t] = v;
    __syncthreads();
    for (int o = 1; o < 256; o <<= 1) {
        int add = (t >= o) ? s[t - o] : 0;
        __syncthreads();
        s[t] += add;
        __syncthreads();
    }
    int ex = s[t] - v;
    cur[t] = ex;
    int node = node0 + t;
    if (node < n) {
        rowstart[node] = e0 + ex;
        deg[node] = v;                       // in-degree (no self-loop)
        dis[node] = rsqrtf((float)(v + 1));  // +1 self-loop
    }
    __syncthreads();
    for (int e = e0 + t; e < e1; e += 256) {
        int p = esort[e];
        int pos = atomicAdd(&cur[p & 255], 1);
        col[e0 + pos] = p >> 8;              // src
    }
}

// g1h[r,f] = half((x[r,:] @ W1[:,f]) * dis[r])
// lane = row (64 rows/block), wave w -> features [16w, 16w+16)
__global__ __launch_bounds__(256, 4) void k_gemm1(
    const float* __restrict__ x, const float* __restrict__ W1,
    const float* __restrict__ dis, uint4* __restrict__ g1h, int n) {
    __shared__ float xs[64 * 129];   // pad 129: conflict-free
    int tid  = threadIdx.x;
    int row0 = blockIdx.x * 64;
    for (int i = tid; i < 64 * F_IN; i += 256) {
        int r = i >> 7, k = i & 127;
        int gr = row0 + r;
        xs[r * 129 + k] = (gr < n) ? x[(size_t)gr * F_IN + k] : 0.0f;
    }
    __syncthreads();
    int w = RFL(tid >> 6);
    int r = tid & 63;
    const float4* W4 = (const float4*)W1;   // [128][16] float4 view
    float4 a0 = {0.f,0.f,0.f,0.f}, a1 = a0, a2 = a0, a3 = a0;
#pragma unroll 4
    for (int k = 0; k < F_IN; ++k) {
        float xv = xs[r * 129 + k];
        float4 w0 = W4[k * 16 + w * 4 + 0];
        float4 w1 = W4[k * 16 + w * 4 + 1];
        float4 w2 = W4[k * 16 + w * 4 + 2];
        float4 w3 = W4[k * 16 + w * 4 + 3];
        a0.x += xv * w0.x; a0.y += xv * w0.y; a0.z += xv * w0.z; a0.w += xv * w0.w;
        a1.x += xv * w1.x; a1.y += xv * w1.y; a1.z += xv * w1.z; a1.w += xv * w1.w;
        a2.x += xv * w2.x; a2.y += xv * w2.y; a2.z += xv * w2.z; a2.w += xv * w2.w;
        a3.x += xv * w3.x; a3.y += xv * w3.y; a3.z += xv * w3.z; a3.w += xv * w3.w;
    }
    int gr = row0 + r;
    if (gr < n) {
        float dv = dis[gr];
        a0.x *= dv; a0.y *= dv; a0.z *= dv; a0.w *= dv;
        a1.x *= dv; a1.y *= dv; a1.z *= dv; a1.w *= dv;
        a2.x *= dv; a2.y *= dv; a2.z *= dv; a2.w *= dv;
        a3.x *= dv; a3.y *= dv; a3.z *= dv; a3.w *= dv;
        g1h[(size_t)gr * 8 + w * 2 + 0] = pack8(a0, a1);
        g1h[(size_t)gr * 8 + w * 2 + 1] = pack8(a2, a3);
    }
}

// ---- Fused gather1 + gemm2 ----
// one wave per dst row. Gather g1h (128 B fp16 rows; q=lane&7, slot=lane>>3,
// 4 loads in flight), reduce -> h[d] in wave; h -> per-wave LDS; then
// g2[d,j] = (h . W2[:,j]) * dis[d], W2 staged in LDS; g2h stored fp16.
__global__ __launch_bounds__(256) void k_gather1_g2(
    const int* __restrict__ rowstart, const int* __restrict__ deg,
    const int* __restrict__ col, const uint4* __restrict__ g1h,
    const float* __restrict__ dis, const float* __restrict__ b1,
    const float* __restrict__ W2, __half* __restrict__ g2h, int n) {
    __shared__ float W2s[F_MID * F_OUT];  // 8 KB
    __shared__ float hrow[4 * F_MID];     // 1 KB (per-wave h rows)
    int t = threadIdx.x;
    for (int i = t; i < F_MID * F_OUT; i += 256) W2s[i] = W2[i];
    __syncthreads();   // W2s shared cross-wave; barrier before any divergence
    int wave = RFL(t >> 6);
    int lane = t & 63;
    int q    = lane & 7;    // features 8q..8q+7
    int slot = lane >> 3;   // 0..7
    int d    = blockIdx.x * 4 + wave;
    if (d < n) {            // wave-uniform branch (d uniform per wave)
        int base = RFL(rowstart[d]);
        int cnt  = RFL(deg[d]);
        float a[8] = {0,0,0,0,0,0,0,0};
        float b[8] = {0,0,0,0,0,0,0,0};
        if (slot == 0) {                   // self-loop
            uint4 v = g1h[(size_t)d * 8 + q];
            h8acc(a, v);
        }
        int j = 0;
        for (; j + 32 <= cnt; j += 32) {
            int s0 = col[base + j + slot];
            int s1 = col[base + j + 8 + slot];
            int s2 = col[base + j + 16 + slot];
            int s3 = col[base + j + 24 + slot];
            uint4 v0 = g1h[(size_t)s0 * 8 + q];
            uint4 v1 = g1h[(size_t)s1 * 8 + q];
            uint4 v2 = g1h[(size_t)s2 * 8 + q];
            uint4 v3 = g1h[(size_t)s3 * 8 + q];
            h8acc(a, v0); h8acc(b, v1); h8acc(a, v2); h8acc(b, v3);
        }
        for (; j + 16 <= cnt; j += 16) {
            int s0 = col[base + j + slot];
            int s1 = col[base + j + 8 + slot];
            uint4 v0 = g1h[(size_t)s0 * 8 + q];
            uint4 v1 = g1h[(size_t)s1 * 8 + q];
            h8acc(a, v0); h8acc(b, v1);
        }
        for (; j + 8 <= cnt; j += 8) {
            int s = col[base + j + slot];
            uint4 v = g1h[(size_t)s * 8 + q];
            h8acc(a, v);
        }
        if (slot < cnt - j) {
            int s = col[base + j + slot];
            uint4 v = g1h[(size_t)s * 8 + q];
            h8acc(a, v);
        }
#pragma unroll
        for (int i = 0; i < 8; ++i) a[i] += b[i];
#pragma unroll
        for (int i = 0; i < 8; ++i) a[i] += __shfl_xor(a[i], 8);
#pragma unroll
        for (int i = 0; i < 8; ++i) a[i] += __shfl_xor(a[i], 16);
#pragma unroll
        for (int i = 0; i < 8; ++i) a[i] += __shfl_xor(a[i], 32);
        float dv = dis[d];
        if (slot == 0) {   // lanes 0..7 hold h[d] features 8q..8q+7
            float4 bv0 = ((const float4*)b1)[q * 2 + 0];
            float4 bv1 = ((const float4*)b1)[q * 2 + 1];
            float* hp = &hrow[wave * F_MID + q * 8];
            hp[0] = fmaxf(a[0] * dv + bv0.x, 0.f);
            hp[1] = fmaxf(a[1] * dv + bv0.y, 0.f);
            hp[2] = fmaxf(a[2] * dv + bv0.z, 0.f);
            hp[3] = fmaxf(a[3] * dv + bv0.w, 0.f);
            hp[4] = fmaxf(a[4] * dv + bv1.x, 0.f);
            hp[5] = fmaxf(a[5] * dv + bv1.y, 0.f);
            hp[6] = fmaxf(a[6] * dv + bv1.z, 0.f);
            hp[7] = fmaxf(a[7] * dv + bv1.w, 0.f);
        }
        // same-wave LDS dependency: compiler inserts lgkmcnt wait
        int jo = lane & 31;   // output feature
        int kh = lane >> 5;   // k-half 0/1
        float acc2 = 0.f;
        const float* hb = &hrow[wave * F_MID + kh * 32];
        const float* wb = &W2s[kh * 32 * F_OUT + jo];
#pragma unroll 8
        for (int k = 0; k < 32; ++k)
            acc2 += hb[k] * wb[k * F_OUT];
        acc2 += __shfl_xor(acc2, 32);
        if (lane < 32)
            g2h[(size_t)d * F_OUT + jo] = __float2half(acc2 * dv);
    }
}

// one wave per dst row. fp16 row = 64 B = 4 x uint4. q=lane&3, slot=lane>>2.
__global__ __launch_bounds__(256) void k_gather2(
    const int* __restrict__ rowstart, const int* __restrict__ deg,
    const int* __restrict__ col, const uint4* __restrict__ g2h,
    const float* __restrict__ dis, const float* __restrict__ b2,
    float* __restrict__ out, int n) {
    int wave = RFL(threadIdx.x >> 6);
    int lane = threadIdx.x & 63;
    int q    = lane & 3;    // features 8q..8q+7
    int slot = lane >> 2;   // 0..15
    int d    = blockIdx.x * 4 + wave;
    if (d >= n) return;
    int base = RFL(rowstart[d]);
    int cnt  = RFL(deg[d]);
    float a[8] = {0,0,0,0,0,0,0,0};
    float b[8] = {0,0,0,0,0,0,0,0};
    if (slot == 0) {                       // self-loop
        uint4 v = g2h[(size_t)d * 4 + q];
        h8acc(a, v);
    }
    int j = 0;
    for (; j + 64 <= cnt; j += 64) {
        int s0 = col[base + j + slot];
        int s1 = col[base + j + 16 + slot];
        int s2 = col[base + j + 32 + slot];
        int s3 = col[base + j + 48 + slot];
        uint4 v0 = g2h[(size_t)s0 * 4 + q];
        uint4 v1 = g2h[(size_t)s1 * 4 + q];
        uint4 v2 = g2h[(size_t)s2 * 4 + q];
        uint4 v3 = g2h[(size_t)s3 * 4 + q];
        h8acc(a, v0); h8acc(b, v1); h8acc(a, v2); h8acc(b, v3);
    }
    for (; j + 32 <= cnt; j += 32) {
        int s0 = col[base + j + slot];
        int s1 = col[base + j + 16 + slot];
        uint4 v0 = g2h[(size_t)s0 * 4 + q];
        uint4 v1 = g2h[(size_t)s1 * 4 + q];
        h8acc(a, v0); h8acc(b, v1);
    }
    for (; j + 16 <= cnt; j += 16) {
        int s = col[base + j + slot];
        uint4 v = g2h[(size_t)s * 4 + q];
        h8acc(a, v);
    }
    if (slot < cnt - j) {
        int s = col[base + j + slot];
        uint4 v = g2h[(size_t)s * 4 + q];
        h8acc(a, v);
    }
#pragma unroll
    for (int i = 0; i < 8; ++i) a[i] += b[i];
#pragma unroll
    for (int i = 0; i < 8; ++i) a[i] += __shfl_xor(a[i], 4);
#pragma unroll
    for (int i = 0; i < 8; ++i) a[i] += __shfl_xor(a[i], 8);
#pragma unroll
    for (int i = 0; i < 8; ++i) a[i] += __shfl_xor(a[i], 16);
#pragma unroll
    for (int i = 0; i < 8; ++i) a[i] += __shfl_xor(a[i], 32);
    if (slot == 0) {
        float dv = dis[d];
        float4 bv0 = ((const float4*)b2)[q * 2 + 0];
        float4 bv1 = ((const float4*)b2)[q * 2 + 1];
        float4 o0, o1;
        o0.x = a[0] * dv + bv0.x;
        o0.y = a[1] * dv + bv0.y;
        o0.z = a[2] * dv + bv0.z;
        o0.w = a[3] * dv + bv0.w;
        o1.x = a[4] * dv + bv1.x;
        o1.y = a[5] * dv + bv1.y;
        o1.z = a[6] * dv + bv1.z;
        o1.w = a[7] * dv + bv1.w;
        float4* O4 = (float4*)out;
        O4[(size_t)d * 8 + q * 2 + 0] = o0;
        O4[(size_t)d * 8 + q * 2 + 1] = o1;
    }
}

extern "C" void kernel_launch(void* const* d_in, const int* in_sizes, int n_in,
                              void* d_out, int out_size, void* d_ws, size_t ws_size,
                              hipStream_t stream) {
    const float* x  = (const float*)d_in[0];
    const int*   ei = (const int*)d_in[1];
    const float* W1 = (const float*)d_in[2];
    const float* b1 = (const float*)d_in[3];
    const float* W2 = (const float*)d_in[4];
    const float* b2 = (const float*)d_in[5];

    int n = in_sizes[0] / F_IN;   // 50000
    int E = in_sizes[1] / 2;      // 800000
    const int* src = ei;
    const int* dst = ei + E;

    int nbuk  = (n + 255) >> 8;   // 196 (must be <= 256)
    int chunk = (E + NBLK - 1) / NBLK;

    char* ws = (char*)d_ws;
    size_t off = 0;
    auto alloc = [&](size_t bytes) {
        char* p = ws + off;
        off += (bytes + 255) & ~(size_t)255;
        return p;
    };
    int*    cursor   = (int*)   alloc((size_t)nbuk * 4);
    int*    esort    = (int*)   alloc((size_t)nbuk * CAP * 4);   // 6.4 MB
    int*    col      = (int*)   alloc((size_t)nbuk * CAP * 4);   // 6.4 MB
    int*    rowstart = (int*)   alloc((size_t)n * 4);
    int*    deg      = (int*)   alloc((size_t)n * 4);
    float*  dis      = (float*) alloc((size_t)n * 4);
    uint4*  g1h      = (uint4*) alloc((size_t)n * F_MID * 2);    // fp16
    __half* g2h      = (__half*)alloc((size_t)n * F_OUT * 2);    // fp16

    hipMemsetAsync(cursor, 0, (size_t)nbuk * 4, stream);
    k_build_scatter<<<NBLK, 256, 0, stream>>>(src, dst, E, chunk, nbuk, cursor, esort);
    k_bucket_csr<<<nbuk, 256, 0, stream>>>(esort, cursor, n, rowstart, deg, dis, col);

    k_gemm1<<<(n + 63) / 64, 256, 0, stream>>>(x, W1, dis, g1h, n);
    k_gather1_g2<<<(n + 3) / 4, 256, 0, stream>>>(rowstart, deg, col, g1h, dis, b1,
                                                  W2, g2h, n);
    k_gather2<<<(n + 3) / 4, 256, 0, stream>>>(rowstart, deg, col, (const uint4*)g2h,
                                               dis, b2, (float*)d_out, n);
}

// Round 12
// 181.817 us; speedup vs baseline: 1.0404x; 1.0404x over previous
//
#include <hip/hip_runtime.h>
#include <hip/hip_fp16.h>

// GCN 2-layer: x[N,128] -> GCNConv(W1[128,64]) -> relu -> GCNConv(W2[64,32])
// out[d] = dis[d] * (g[d] + sum_{e: dst=d} g[src]) + b,  g = (x@W)*dis.
// R11: R9 compute pipeline (best known) + R10's 2-kernel build only
//      (fixed-CAP bucket reservation; hist+2 scans+scatter -> 1 kernel).
//      R10's gemm2-fusion reverted (it lengthened the gather critical path).

#define F_IN 128
#define F_MID 64
#define F_OUT 32
#define NBLK 256
#define CAP 8192   // max edges/bucket: mean 4096, tail ~4500 -> safe

#define RFL(x) __builtin_amdgcn_readfirstlane(x)

// add 8 halves (as uint4) into float a[8]
__device__ __forceinline__ void h8acc(float* a, const uint4& v) {
    const __half2* hp = (const __half2*)&v;
#pragma unroll
    for (int i = 0; i < 4; ++i) {
        float2 f = __half22float2(hp[i]);
        a[2 * i]     += f.x;
        a[2 * i + 1] += f.y;
    }
}

__device__ __forceinline__ void h8unpack(float* f, const uint4& v) {
    const __half2* hp = (const __half2*)&v;
#pragma unroll
    for (int i = 0; i < 4; ++i) {
        float2 t = __half22float2(hp[i]);
        f[2 * i]     = t.x;
        f[2 * i + 1] = t.y;
    }
}

__device__ __forceinline__ uint4 pack8(const float4& a, const float4& b) {
    union { uint4 u; __half2 h[4]; } pk;
    pk.h[0] = __float22half2_rn(make_float2(a.x, a.y));
    pk.h[1] = __float22half2_rn(make_float2(a.z, a.w));
    pk.h[2] = __float22half2_rn(make_float2(b.x, b.y));
    pk.h[3] = __float22half2_rn(make_float2(b.z, b.w));
    return pk.u;
}

// ---- Build pass 1: LDS histogram + atomic chunk reservation + scatter ----
__global__ __launch_bounds__(256) void k_build_scatter(
    const int* __restrict__ src, const int* __restrict__ dst, int E, int chunk,
    int nbuk, int* __restrict__ cursor, int* __restrict__ esort) {
    __shared__ int cnt[256];
    __shared__ int off[256];
    int t = threadIdx.x;
    cnt[t] = 0;
    __syncthreads();
    int e0 = blockIdx.x * chunk;
    int e1 = min(E, e0 + chunk);
    for (int e = e0 + t; e < e1; e += 256)
        atomicAdd(&cnt[dst[e] >> 8], 1);
    __syncthreads();
    if (t < nbuk) {
        int c = cnt[t];
        off[t] = t * CAP + (c ? atomicAdd(&cursor[t], c) : 0);
    }
    __syncthreads();
    for (int e = e0 + t; e < e1; e += 256) {
        int d = dst[e];
        int pos = atomicAdd(&off[d >> 8], 1);
        esort[pos] = (src[e] << 8) | (d & 255);   // src < 2^24
    }
}

// ---- Build pass 2: per-bucket exact CSR: deg, rowstart, dis, ordered col ----
__global__ __launch_bounds__(256) void k_bucket_csr(
    const int* __restrict__ esort, const int* __restrict__ cursor, int n,
    int* __restrict__ rowstart, int* __restrict__ deg, float* __restrict__ dis,
    int* __restrict__ col) {
    __shared__ int cnt[256];
    __shared__ int s[256];
    __shared__ int cur[256];
    int b = blockIdx.x;
    int t = threadIdx.x;
    int node0 = b << 8;
    int e0 = b * CAP;
    int e1 = e0 + cursor[b];
    cnt[t] = 0;
    __syncthreads();
    for (int e = e0 + t; e < e1; e += 256)
        atomicAdd(&cnt[esort[e] & 255], 1);
    __syncthreads();
    int v = cnt[t];
    s[t] = v;
    __syncthreads();
    for (int o = 1; o < 256; o <<= 1) {
        int add = (t >= o) ? s[t - o] : 0;
        __syncthreads();
        s[t] += add;
        __syncthreads();
    }
    int ex = s[t] - v;
    cur[t] = ex;
    int node = node0 + t;
    if (node < n) {
        rowstart[node] = e0 + ex;
        deg[node] = v;                       // in-degree (no self-loop)
        dis[node] = rsqrtf((float)(v + 1));  // +1 self-loop
    }
    __syncthreads();
    for (int e = e0 + t; e < e1; e += 256) {
        int p = esort[e];
        int pos = atomicAdd(&cur[p & 255], 1);
        col[e0 + pos] = p >> 8;              // src (non-negative)
    }
}

// g1h[r,f] = half((x[r,:] @ W1[:,f]) * dis[r])
// lane = row (64 rows/block), wave w -> features [16w, 16w+16)
__global__ __launch_bounds__(256, 4) void k_gemm1(
    const float* __restrict__ x, const float* __restrict__ W1,
    const float* __restrict__ dis, uint4* __restrict__ g1h, int n) {
    __shared__ float xs[64 * 129];   // pad 129: conflict-free
    int tid  = threadIdx.x;
    int row0 = blockIdx.x * 64;
    for (int i = tid; i < 64 * F_IN; i += 256) {
        int r = i >> 7, k = i & 127;
        int gr = row0 + r;
        xs[r * 129 + k] = (gr < n) ? x[(size_t)gr * F_IN + k] : 0.0f;
    }
    __syncthreads();
    int w = RFL(tid >> 6);
    int r = tid & 63;
    const float4* W4 = (const float4*)W1;   // [128][16] float4 view
    float4 a0 = {0.f,0.f,0.f,0.f}, a1 = a0, a2 = a0, a3 = a0;
#pragma unroll 4
    for (int k = 0; k < F_IN; ++k) {
        float xv = xs[r * 129 + k];
        float4 w0 = W4[k * 16 + w * 4 + 0];
        float4 w1 = W4[k * 16 + w * 4 + 1];
        float4 w2 = W4[k * 16 + w * 4 + 2];
        float4 w3 = W4[k * 16 + w * 4 + 3];
        a0.x += xv * w0.x; a0.y += xv * w0.y; a0.z += xv * w0.z; a0.w += xv * w0.w;
        a1.x += xv * w1.x; a1.y += xv * w1.y; a1.z += xv * w1.z; a1.w += xv * w1.w;
        a2.x += xv * w2.x; a2.y += xv * w2.y; a2.z += xv * w2.z; a2.w += xv * w2.w;
        a3.x += xv * w3.x; a3.y += xv * w3.y; a3.z += xv * w3.z; a3.w += xv * w3.w;
    }
    int gr = row0 + r;
    if (gr < n) {
        float dv = dis[gr];
        a0.x *= dv; a0.y *= dv; a0.z *= dv; a0.w *= dv;
        a1.x *= dv; a1.y *= dv; a1.z *= dv; a1.w *= dv;
        a2.x *= dv; a2.y *= dv; a2.z *= dv; a2.w *= dv;
        a3.x *= dv; a3.y *= dv; a3.z *= dv; a3.w *= dv;
        g1h[(size_t)gr * 8 + w * 2 + 0] = pack8(a0, a1);
        g1h[(size_t)gr * 8 + w * 2 + 1] = pack8(a2, a3);
    }
}

// one wave per dst row. fp16 row = 128 B = 8 x uint4. q=lane&7, slot=lane>>3.
// Up to 4 independent uint4 loads in flight. h stored fp16.
__global__ __launch_bounds__(256) void k_gather1(
    const int* __restrict__ rowstart, const int* __restrict__ deg,
    const int* __restrict__ col, const uint4* __restrict__ g1h,
    const float* __restrict__ dis, const float* __restrict__ b1,
    uint4* __restrict__ h16, int n) {
    int wave = RFL(threadIdx.x >> 6);
    int lane = threadIdx.x & 63;
    int q    = lane & 7;    // features 8q..8q+7
    int slot = lane >> 3;   // 0..7
    int d    = blockIdx.x * 4 + wave;
    if (d >= n) return;
    int base = RFL(rowstart[d]);
    int cnt  = RFL(deg[d]);
    float a[8] = {0,0,0,0,0,0,0,0};
    float b[8] = {0,0,0,0,0,0,0,0};
    if (slot == 0) {                       // self-loop
        uint4 v = g1h[(size_t)d * 8 + q];
        h8acc(a, v);
    }
    int j = 0;
    for (; j + 32 <= cnt; j += 32) {
        int s0 = col[base + j + slot];
        int s1 = col[base + j + 8 + slot];
        int s2 = col[base + j + 16 + slot];
        int s3 = col[base + j + 24 + slot];
        uint4 v0 = g1h[(size_t)s0 * 8 + q];
        uint4 v1 = g1h[(size_t)s1 * 8 + q];
        uint4 v2 = g1h[(size_t)s2 * 8 + q];
        uint4 v3 = g1h[(size_t)s3 * 8 + q];
        h8acc(a, v0); h8acc(b, v1); h8acc(a, v2); h8acc(b, v3);
    }
    for (; j + 16 <= cnt; j += 16) {
        int s0 = col[base + j + slot];
        int s1 = col[base + j + 8 + slot];
        uint4 v0 = g1h[(size_t)s0 * 8 + q];
        uint4 v1 = g1h[(size_t)s1 * 8 + q];
        h8acc(a, v0); h8acc(b, v1);
    }
    for (; j + 8 <= cnt; j += 8) {
        int s = col[base + j + slot];
        uint4 v = g1h[(size_t)s * 8 + q];
        h8acc(a, v);
    }
    if (slot < cnt - j) {
        int s = col[base + j + slot];
        uint4 v = g1h[(size_t)s * 8 + q];
        h8acc(a, v);
    }
#pragma unroll
    for (int i = 0; i < 8; ++i) a[i] += b[i];
#pragma unroll
    for (int i = 0; i < 8; ++i) a[i] += __shfl_xor(a[i], 8);
#pragma unroll
    for (int i = 0; i < 8; ++i) a[i] += __shfl_xor(a[i], 16);
#pragma unroll
    for (int i = 0; i < 8; ++i) a[i] += __shfl_xor(a[i], 32);
    if (slot == 0) {
        float dv = dis[d];
        float4 bv0 = ((const float4*)b1)[q * 2 + 0];
        float4 bv1 = ((const float4*)b1)[q * 2 + 1];
        float4 o0, o1;
        o0.x = fmaxf(a[0] * dv + bv0.x, 0.f);
        o0.y = fmaxf(a[1] * dv + bv0.y, 0.f);
        o0.z = fmaxf(a[2] * dv + bv0.z, 0.f);
        o0.w = fmaxf(a[3] * dv + bv0.w, 0.f);
        o1.x = fmaxf(a[4] * dv + bv1.x, 0.f);
        o1.y = fmaxf(a[5] * dv + bv1.y, 0.f);
        o1.z = fmaxf(a[6] * dv + bv1.z, 0.f);
        o1.w = fmaxf(a[7] * dv + bv1.w, 0.f);
        h16[(size_t)d * 8 + q] = pack8(o0, o1);
    }
}

// g2h[r,j] = half((h[r,:] @ W2[:,j]) * dis[r]); h input fp16
// lane = row (64 rows/block), wave w -> features [8w, 8w+8)
__global__ __launch_bounds__(256, 4) void k_gemm2(
    const uint4* __restrict__ h16, const float* __restrict__ W2,
    const float* __restrict__ dis, uint4* __restrict__ g2h, int n) {
    __shared__ float hs[64 * 65];    // pad 65: conflict-free
    int tid  = threadIdx.x;
    int row0 = blockIdx.x * 64;
    for (int i = tid; i < 64 * 8; i += 256) {
        int r = i >> 3, q = i & 7;
        int gr = row0 + r;
        float f[8] = {0,0,0,0,0,0,0,0};
        if (gr < n) {
            uint4 v = h16[(size_t)gr * 8 + q];
            h8unpack(f, v);
        }
        float* p = &hs[r * 65 + q * 8];
#pragma unroll
        for (int k = 0; k < 8; ++k) p[k] = f[k];
    }
    __syncthreads();
    int w = RFL(tid >> 6);
    int r = tid & 63;
    const float4* W4 = (const float4*)W2;   // [64][8] float4 view
    float4 a0 = {0.f,0.f,0.f,0.f}, a1 = a0;
#pragma unroll 4
    for (int k = 0; k < F_MID; ++k) {
        float hv = hs[r * 65 + k];
        float4 w0 = W4[k * 8 + w * 2 + 0];
        float4 w1 = W4[k * 8 + w * 2 + 1];
        a0.x += hv * w0.x; a0.y += hv * w0.y; a0.z += hv * w0.z; a0.w += hv * w0.w;
        a1.x += hv * w1.x; a1.y += hv * w1.y; a1.z += hv * w1.z; a1.w += hv * w1.w;
    }
    int gr = row0 + r;
    if (gr < n) {
        float dv = dis[gr];
        a0.x *= dv; a0.y *= dv; a0.z *= dv; a0.w *= dv;
        a1.x *= dv; a1.y *= dv; a1.z *= dv; a1.w *= dv;
        g2h[(size_t)gr * 4 + w] = pack8(a0, a1);
    }
}

// one wave per dst row. fp16 row = 64 B = 4 x uint4. q=lane&3, slot=lane>>2.
__global__ __launch_bounds__(256) void k_gather2(
    const int* __restrict__ rowstart, const int* __restrict__ deg,
    const int* __restrict__ col, const uint4* __restrict__ g2h,
    const float* __restrict__ dis, const float* __restrict__ b2,
    float* __restrict__ out, int n) {
    int wave = RFL(threadIdx.x >> 6);
    int lane = threadIdx.x & 63;
    int q    = lane & 3;    // features 8q..8q+7
    int slot = lane >> 2;   // 0..15
    int d    = blockIdx.x * 4 + wave;
    if (d >= n) return;
    int base = RFL(rowstart[d]);
    int cnt  = RFL(deg[d]);
    float a[8] = {0,0,0,0,0,0,0,0};
    float b[8] = {0,0,0,0,0,0,0,0};
    if (slot == 0) {                       // self-loop
        uint4 v = g2h[(size_t)d * 4 + q];
        h8acc(a, v);
    }
    int j = 0;
    for (; j + 64 <= cnt; j += 64) {
        int s0 = col[base + j + slot];
        int s1 = col[base + j + 16 + slot];
        int s2 = col[base + j + 32 + slot];
        int s3 = col[base + j + 48 + slot];
        uint4 v0 = g2h[(size_t)s0 * 4 + q];
        uint4 v1 = g2h[(size_t)s1 * 4 + q];
        uint4 v2 = g2h[(size_t)s2 * 4 + q];
        uint4 v3 = g2h[(size_t)s3 * 4 + q];
        h8acc(a, v0); h8acc(b, v1); h8acc(a, v2); h8acc(b, v3);
    }
    for (; j + 32 <= cnt; j += 32) {
        int s0 = col[base + j + slot];
        int s1 = col[base + j + 16 + slot];
        uint4 v0 = g2h[(size_t)s0 * 4 + q];
        uint4 v1 = g2h[(size_t)s1 * 4 + q];
        h8acc(a, v0); h8acc(b, v1);
    }
    for (; j + 16 <= cnt; j += 16) {
        int s = col[base + j + slot];
        uint4 v = g2h[(size_t)s * 4 + q];
        h8acc(a, v);
    }
    if (slot < cnt - j) {
        int s = col[base + j + slot];
        uint4 v = g2h[(size_t)s * 4 + q];
        h8acc(a, v);
    }
#pragma unroll
    for (int i = 0; i < 8; ++i) a[i] += b[i];
#pragma unroll
    for (int i = 0; i < 8; ++i) a[i] += __shfl_xor(a[i], 4);
#pragma unroll
    for (int i = 0; i < 8; ++i) a[i] += __shfl_xor(a[i], 8);
#pragma unroll
    for (int i = 0; i < 8; ++i) a[i] += __shfl_xor(a[i], 16);
#pragma unroll
    for (int i = 0; i < 8; ++i) a[i] += __shfl_xor(a[i], 32);
    if (slot == 0) {
        float dv = dis[d];
        float4 bv0 = ((const float4*)b2)[q * 2 + 0];
        float4 bv1 = ((const float4*)b2)[q * 2 + 1];
        float4 o0, o1;
        o0.x = a[0] * dv + bv0.x;
        o0.y = a[1] * dv + bv0.y;
        o0.z = a[2] * dv + bv0.z;
        o0.w = a[3] * dv + bv0.w;
        o1.x = a[4] * dv + bv1.x;
        o1.y = a[5] * dv + bv1.y;
        o1.z = a[6] * dv + bv1.z;
        o1.w = a[7] * dv + bv1.w;
        float4* O4 = (float4*)out;
        O4[(size_t)d * 8 + q * 2 + 0] = o0;
        O4[(size_t)d * 8 + q * 2 + 1] = o1;
    }
}

extern "C" void kernel_launch(void* const* d_in, const int* in_sizes, int n_in,
                              void* d_out, int out_size, void* d_ws, size_t ws_size,
                              hipStream_t stream) {
    const float* x  = (const float*)d_in[0];
    const int*   ei = (const int*)d_in[1];
    const float* W1 = (const float*)d_in[2];
    const float* b1 = (const float*)d_in[3];
    const float* W2 = (const float*)d_in[4];
    const float* b2 = (const float*)d_in[5];

    int n = in_sizes[0] / F_IN;   // 50000
    int E = in_sizes[1] / 2;      // 800000
    const int* src = ei;
    const int* dst = ei + E;

    int nbuk  = (n + 255) >> 8;   // 196 (must be <= 256)
    int chunk = (E + NBLK - 1) / NBLK;

    char* ws = (char*)d_ws;
    size_t off = 0;
    auto alloc = [&](size_t bytes) {
        char* p = ws + off;
        off += (bytes + 255) & ~(size_t)255;
        return p;
    };
    int*   cursor   = (int*)  alloc((size_t)nbuk * 4);
    int*   esort    = (int*)  alloc((size_t)nbuk * CAP * 4);   // 6.4 MB
    int*   col      = (int*)  alloc((size_t)nbuk * CAP * 4);   // 6.4 MB
    int*   rowstart = (int*)  alloc((size_t)n * 4);
    int*   deg      = (int*)  alloc((size_t)n * 4);
    float* dis      = (float*)alloc((size_t)n * 4);
    uint4* g1h      = (uint4*)alloc((size_t)n * F_MID * 2);    // fp16
    uint4* h16      = (uint4*)alloc((size_t)n * F_MID * 2);    // fp16
    uint4* g2h      = (uint4*)alloc((size_t)n * F_OUT * 2);    // fp16

    hipMemsetAsync(cursor, 0, (size_t)nbuk * 4, stream);
    k_build_scatter<<<NBLK, 256, 0, stream>>>(src, dst, E, chunk, nbuk, cursor, esort);
    k_bucket_csr<<<nbuk, 256, 0, stream>>>(esort, cursor, n, rowstart, deg, dis, col);

    k_gemm1<<<(n + 63) / 64, 256, 0, stream>>>(x, W1, dis, g1h, n);
    k_gather1<<<(n + 3) / 4, 256, 0, stream>>>(rowstart, deg, col, g1h, dis, b1, h16, n);
    k_gemm2<<<(n + 63) / 64, 256, 0, stream>>>(h16, W2, dis, g2h, n);
    k_gather2<<<(n + 3) / 4, 256, 0, stream>>>(rowstart, deg, col, g2h, dis, b2,
                                               (float*)d_out, n);
}